// Round 1
// baseline (934.147 us; speedup 1.0000x reference)
//
#include <hip/hip_runtime.h>
#include <math.h>

static constexpr int NN = 100000;   // nodes
static constexpr int NE = 1600000;  // edges

__global__ void k_fill1(float* __restrict__ p, int n) {
  int i = blockIdx.x * blockDim.x + threadIdx.x;
  if (i < n) p[i] = 1.0f;
}

// deg[dst] += 1 for each edge (deg initialized to 1.0 for the self loop)
__global__ void k_degacc(const int* __restrict__ ei, float* __restrict__ deg) {
  int e = blockIdx.x * blockDim.x + threadIdx.x;
  if (e < NE) atomicAdd(&deg[ei[NE + e]], 1.0f);
}

__global__ void k_rsqrt(float* __restrict__ p, int n) {
  int i = blockIdx.x * blockDim.x + threadIdx.x;
  if (i < n) p[i] = rsqrtf(p[i]);  // deg >= 1 always (self loop)
}

// g[row][c] = (sum_k in[row][k] * W[k][c]) * dis[row]
template<int K, int C>
__global__ void k_gemm_scale(const float* __restrict__ in, const float* __restrict__ W,
                             const float* __restrict__ dis, float* __restrict__ g) {
  __shared__ float Ws[K * C];
  for (int t = threadIdx.x; t < K * C; t += blockDim.x) Ws[t] = W[t];
  __syncthreads();
  constexpr int R = 256 / (C > 256 ? 256 : C);  // rows per block
  int t = threadIdx.x;
  int rl = t / C, c = t % C;
  int row = blockIdx.x * R + rl;
  if (row >= NN) return;
  const float* inr = in + row * K;
  float acc = 0.f;
#pragma unroll
  for (int k = 0; k < K; ++k) acc += inr[k] * Ws[k * C + c];
  g[row * C + c] = acc * dis[row];
}

__global__ void k_copy(const float* __restrict__ a, float* __restrict__ b, int n) {
  int i = blockIdx.x * blockDim.x + threadIdx.x;
  if (i < n) b[i] = a[i];
}

// agg[dst][c] += g[src][c] for every edge
template<int C>
__global__ void k_scatter(const int* __restrict__ ei, const float* __restrict__ g,
                          float* __restrict__ agg) {
  int t = blockIdx.x * blockDim.x + threadIdx.x;
  if (t >= NE * C) return;        // max 102.4M, fits int32
  int e = t / C, c = t % C;       // C is a power of two -> shifts
  int src = ei[e], dst = ei[NE + e];
  atomicAdd(&agg[dst * C + c], g[src * C + c]);
}

// out = (maybe tanh)(agg * dis[row] + b[c]); may run in place (out == agg)
template<int C, bool TANH>
__global__ void k_epi(const float* __restrict__ agg, const float* __restrict__ dis,
                      const float* __restrict__ b, float* __restrict__ out) {
  int t = blockIdx.x * blockDim.x + threadIdx.x;
  if (t >= NN * C) return;
  int row = t / C, c = t % C;
  float v = agg[t] * dis[row] + b[c];
  out[t] = TANH ? tanhf(v) : v;
}

extern "C" void kernel_launch(void* const* d_in, const int* in_sizes, int n_in,
                              void* d_out, int out_size, void* d_ws, size_t ws_size,
                              hipStream_t stream) {
  const float* x  = (const float*)d_in[0];
  const int*   ei = (const int*)d_in[1];   // [2, NE] int32 (JAX x64 off)
  const float* W1 = (const float*)d_in[2];
  const float* b1 = (const float*)d_in[3];
  const float* W2 = (const float*)d_in[4];
  const float* b2 = (const float*)d_in[5];
  const float* W3 = (const float*)d_in[6];
  const float* b3 = (const float*)d_in[7];
  float* out = (float*)d_out;

  float* ws  = (float*)d_ws;
  float* dis = ws;                 // N floats (deg, then rsqrt in place)
  float* A   = ws + 100352;        // N*64 floats: g buffer
  float* B   = A + NN * 64;        // N*64 floats: agg / h buffer
  // total: (100352 + 12,800,000) * 4 B ~= 49.2 MiB of d_ws

  // ---- gcn_norm: deg -> dis = deg^-1/2
  k_fill1 <<<(NN + 255) / 256, 256, 0, stream>>>(dis, NN);
  k_degacc<<<(NE + 255) / 256, 256, 0, stream>>>(ei, dis);
  k_rsqrt <<<(NN + 255) / 256, 256, 0, stream>>>(dis, NN);

  // ---- layer 1: 64 -> 64, tanh
  k_gemm_scale<64, 64><<<(NN + 3) / 4, 256, 0, stream>>>(x, W1, dis, A);
  k_copy<<<(NN * 64 + 255) / 256, 256, 0, stream>>>(A, B, NN * 64);   // self loop
  k_scatter<64><<<(NE * 64 + 255) / 256, 256, 0, stream>>>(ei, A, B);
  k_epi<64, true><<<(NN * 64 + 255) / 256, 256, 0, stream>>>(B, dis, b1, B);

  // ---- layer 2: 64 -> 32, tanh
  k_gemm_scale<64, 32><<<(NN + 7) / 8, 256, 0, stream>>>(B, W2, dis, A);
  k_copy<<<(NN * 32 + 255) / 256, 256, 0, stream>>>(A, B, NN * 32);
  k_scatter<32><<<(NE * 32 + 255) / 256, 256, 0, stream>>>(ei, A, B);
  k_epi<32, true><<<(NN * 32 + 255) / 256, 256, 0, stream>>>(B, dis, b2, B);

  // ---- layer 3: 32 -> 1 (no activation), result -> d_out
  k_gemm_scale<32, 1><<<(NN + 255) / 256, 256, 0, stream>>>(B, W3, dis, A);
  k_copy<<<(NN + 255) / 256, 256, 0, stream>>>(A, B, NN);
  k_scatter<1><<<(NE + 255) / 256, 256, 0, stream>>>(ei, A, B);
  k_epi<1, false><<<(NN + 255) / 256, 256, 0, stream>>>(B, dis, b3, out);
}

// Round 2
// 824.268 us; speedup vs baseline: 1.1333x; 1.1333x over previous
//
#include <hip/hip_runtime.h>
#include <math.h>

static constexpr int NN = 100000;   // nodes
static constexpr int NE = 1600000;  // edges

__global__ void k_zero(int* __restrict__ p, int n) {
  int i = blockIdx.x * blockDim.x + threadIdx.x;
  if (i < n) p[i] = 0;
}

// cnt[dst] += 1 (int histogram of incoming edges, excl. self loop)
__global__ void k_deg(const int* __restrict__ ei, int* __restrict__ cnt) {
  int e = blockIdx.x * blockDim.x + threadIdx.x;
  if (e < NE) atomicAdd(&cnt[ei[NE + e]], 1);
}

// single-block exclusive scan: rowptr[0..NN] from cnt[0..NN-1]
__global__ __launch_bounds__(1024)
void k_scan(const int* __restrict__ cnt, int* __restrict__ rowptr) {
  __shared__ int buf[1024];
  __shared__ int s_carry;
  int tid = threadIdx.x;
  if (tid == 0) s_carry = 0;
  __syncthreads();
  for (int base = 0; base < NN; base += 1024) {
    int i = base + tid;
    int v = (i < NN) ? cnt[i] : 0;
    buf[tid] = v;
    __syncthreads();
#pragma unroll
    for (int off = 1; off < 1024; off <<= 1) {
      int t = (tid >= off) ? buf[tid - off] : 0;
      __syncthreads();
      buf[tid] += t;
      __syncthreads();
    }
    int incl = buf[tid];
    int carry = s_carry;
    if (i < NN) rowptr[i] = carry + incl - v;
    __syncthreads();
    if (tid == 1023) s_carry = carry + buf[1023];
    __syncthreads();
  }
  if (tid == 0) rowptr[NN] = s_carry;
}

// dis[i] = rsqrt(1 + cnt[i]); then recycle cnt[] as the fill cursor (= rowptr[i])
__global__ void k_dis_cursor(int* __restrict__ cnt, const int* __restrict__ rowptr,
                             float* __restrict__ dis) {
  int i = blockIdx.x * blockDim.x + threadIdx.x;
  if (i >= NN) return;
  dis[i] = rsqrtf(1.0f + (float)cnt[i]);
  cnt[i] = rowptr[i];
}

// csr_src[cursor[dst]++] = src
__global__ void k_fill(const int* __restrict__ ei, int* __restrict__ cursor,
                       int* __restrict__ csr_src) {
  int e = blockIdx.x * blockDim.x + threadIdx.x;
  if (e >= NE) return;
  int src = ei[e], dst = ei[NE + e];
  int pos = atomicAdd(&cursor[dst], 1);
  csr_src[pos] = src;
}

// g[row][c] = (sum_k in[row][k] * W[k][c]) * dis[row]
template<int K, int C>
__global__ void k_gemm_scale(const float* __restrict__ in, const float* __restrict__ W,
                             const float* __restrict__ dis, float* __restrict__ g) {
  __shared__ float Ws[K * C];
  for (int t = threadIdx.x; t < K * C; t += blockDim.x) Ws[t] = W[t];
  __syncthreads();
  constexpr int R = 256 / (C > 256 ? 256 : C);
  int t = threadIdx.x;
  int rl = t / C, c = t % C;
  int row = blockIdx.x * R + rl;
  if (row >= NN) return;
  const float* inr = in + row * K;
  float acc = 0.f;
#pragma unroll
  for (int k = 0; k < K; ++k) acc += inr[k] * Ws[k * C + c];
  g[row * C + c] = acc * dis[row];
}

// CSR gather-aggregate + self loop + *dis + bias (+tanh), fused.
// C=64: one wave per node (lane == channel).
template<bool TANH>
__global__ void k_agg64(const int* __restrict__ rowptr, const int* __restrict__ csr_src,
                        const float* __restrict__ g, const float* __restrict__ dis,
                        const float* __restrict__ b, float* __restrict__ out) {
  int node = blockIdx.x * 4 + (threadIdx.x >> 6);
  int lane = threadIdx.x & 63;
  if (node >= NN) return;
  float acc = g[node * 64 + lane];           // self loop
  int beg = rowptr[node], end = rowptr[node + 1];
  for (int k = beg; k < end; ++k) {
    int s = csr_src[k];
    acc += g[s * 64 + lane];
  }
  float v = acc * dis[node] + b[lane];
  out[node * 64 + lane] = TANH ? tanhf(v) : v;
}

// C=32: half-wave per node.
template<bool TANH>
__global__ void k_agg32(const int* __restrict__ rowptr, const int* __restrict__ csr_src,
                        const float* __restrict__ g, const float* __restrict__ dis,
                        const float* __restrict__ b, float* __restrict__ out) {
  int node = blockIdx.x * 8 + (threadIdx.x >> 5);
  int lane = threadIdx.x & 31;
  if (node >= NN) return;
  float acc = g[node * 32 + lane];
  int beg = rowptr[node], end = rowptr[node + 1];
  for (int k = beg; k < end; ++k) {
    int s = csr_src[k];
    acc += g[s * 32 + lane];
  }
  float v = acc * dis[node] + b[lane];
  out[node * 32 + lane] = TANH ? tanhf(v) : v;
}

// C=1: thread per node.
__global__ void k_agg1(const int* __restrict__ rowptr, const int* __restrict__ csr_src,
                       const float* __restrict__ g, const float* __restrict__ dis,
                       const float* __restrict__ b, float* __restrict__ out) {
  int node = blockIdx.x * blockDim.x + threadIdx.x;
  if (node >= NN) return;
  float acc = g[node];
  int beg = rowptr[node], end = rowptr[node + 1];
  for (int k = beg; k < end; ++k) acc += g[csr_src[k]];
  out[node] = acc * dis[node] + b[0];
}

extern "C" void kernel_launch(void* const* d_in, const int* in_sizes, int n_in,
                              void* d_out, int out_size, void* d_ws, size_t ws_size,
                              hipStream_t stream) {
  const float* x  = (const float*)d_in[0];
  const int*   ei = (const int*)d_in[1];
  const float* W1 = (const float*)d_in[2];
  const float* b1 = (const float*)d_in[3];
  const float* W2 = (const float*)d_in[4];
  const float* b2 = (const float*)d_in[5];
  const float* W3 = (const float*)d_in[6];
  const float* b3 = (const float*)d_in[7];
  float* out = (float*)d_out;

  char* ws = (char*)d_ws;
  int*   cnt     = (int*)ws;                        ws += ((NN + 1023)/1024)*1024 * 4;
  int*   rowptr  = (int*)ws;                        ws += ((NN + 1 + 1023)/1024)*1024 * 4;
  int*   csr_src = (int*)ws;                        ws += (size_t)NE * 4;
  float* dis     = (float*)ws;                      ws += ((NN + 1023)/1024)*1024 * 4;
  float* A       = (float*)ws;                      ws += (size_t)NN * 64 * 4;  // g buffer
  float* B       = (float*)ws;                      // h buffer
  // total ~ 58.9 MiB of d_ws

  // ---- CSR build + dis
  k_zero<<<(NN + 255) / 256, 256, 0, stream>>>(cnt, NN);
  k_deg <<<(NE + 255) / 256, 256, 0, stream>>>(ei, cnt);
  k_scan<<<1, 1024, 0, stream>>>(cnt, rowptr);
  k_dis_cursor<<<(NN + 255) / 256, 256, 0, stream>>>(cnt, rowptr, dis);
  k_fill<<<(NE + 255) / 256, 256, 0, stream>>>(ei, cnt, csr_src);

  // ---- layer 1: 64 -> 64, tanh
  k_gemm_scale<64, 64><<<(NN + 3) / 4, 256, 0, stream>>>(x, W1, dis, A);
  k_agg64<true><<<(NN + 3) / 4, 256, 0, stream>>>(rowptr, csr_src, A, dis, b1, B);

  // ---- layer 2: 64 -> 32, tanh
  k_gemm_scale<64, 32><<<(NN + 7) / 8, 256, 0, stream>>>(B, W2, dis, A);
  k_agg32<true><<<(NN + 7) / 8, 256, 0, stream>>>(rowptr, csr_src, A, dis, b2, B);

  // ---- layer 3: 32 -> 1 (no activation) -> d_out
  k_gemm_scale<32, 1><<<(NN + 255) / 256, 256, 0, stream>>>(B, W3, dis, A);
  k_agg1<<<(NN + 255) / 256, 256, 0, stream>>>(rowptr, csr_src, A, dis, b3, out);
}

// Round 3
// 643.745 us; speedup vs baseline: 1.4511x; 1.2804x over previous
//
#include <hip/hip_runtime.h>
#include <math.h>

static constexpr int NN = 100000;   // nodes
static constexpr int NE = 1600000;  // edges
static constexpr int SCAN_B = 512;  // nodes per scan block
static constexpr int NB = (NN + SCAN_B - 1) / SCAN_B;  // 196

__global__ void k_zero(int* __restrict__ p, int n) {
  int i = blockIdx.x * blockDim.x + threadIdx.x;
  if (i < n) p[i] = 0;
}

// cnt[dst] += 1 (int histogram of incoming edges, excl. self loop)
__global__ void k_deg(const int* __restrict__ ei, int* __restrict__ cnt) {
  int e = blockIdx.x * blockDim.x + threadIdx.x;
  if (e < NE) atomicAdd(&cnt[ei[NE + e]], 1);
}

// phase 1: per-block local exclusive scan -> rowptr, block sums -> bsum
__global__ __launch_bounds__(SCAN_B)
void k_scan1(const int* __restrict__ cnt, int* __restrict__ rowptr, int* __restrict__ bsum) {
  __shared__ int buf[SCAN_B];
  int tid = threadIdx.x;
  int i = blockIdx.x * SCAN_B + tid;
  int v = (i < NN) ? cnt[i] : 0;
  buf[tid] = v;
  __syncthreads();
#pragma unroll
  for (int off = 1; off < SCAN_B; off <<= 1) {
    int t = (tid >= off) ? buf[tid - off] : 0;
    __syncthreads();
    buf[tid] += t;
    __syncthreads();
  }
  if (i < NN) rowptr[i] = buf[tid] - v;   // exclusive
  if (tid == SCAN_B - 1) bsum[blockIdx.x] = buf[tid];
}

// phase 2: single small block scans the NB block sums (exclusive) -> boff; total -> rowptr[NN]
__global__ __launch_bounds__(256)
void k_scan2(const int* __restrict__ bsum, int* __restrict__ boff, int* __restrict__ rowptr) {
  __shared__ int buf[256];
  int tid = threadIdx.x;
  int v = (tid < NB) ? bsum[tid] : 0;
  buf[tid] = v;
  __syncthreads();
#pragma unroll
  for (int off = 1; off < 256; off <<= 1) {
    int t = (tid >= off) ? buf[tid - off] : 0;
    __syncthreads();
    buf[tid] += t;
    __syncthreads();
  }
  if (tid < NB) boff[tid] = buf[tid] - v;
  if (tid == 255) rowptr[NN] = buf[255];
}

// phase 3: add block offsets; also compute dis and init the fill cursor
__global__ void k_scan3(const int* __restrict__ cnt, const int* __restrict__ boff,
                        int* __restrict__ rowptr, int* __restrict__ cursor,
                        float* __restrict__ dis) {
  int i = blockIdx.x * blockDim.x + threadIdx.x;
  if (i >= NN) return;
  int final = rowptr[i] + boff[i / SCAN_B];
  rowptr[i] = final;
  cursor[i] = final;
  dis[i] = rsqrtf(1.0f + (float)cnt[i]);
}

// csr_src[cursor[dst]++] = src
__global__ void k_fill(const int* __restrict__ ei, int* __restrict__ cursor,
                       int* __restrict__ csr_src) {
  int e = blockIdx.x * blockDim.x + threadIdx.x;
  if (e >= NE) return;
  int src = ei[e], dst = ei[NE + e];
  int pos = atomicAdd(&cursor[dst], 1);
  csr_src[pos] = src;
}

// g[row][c] = (sum_k in[row][k] * W[k][c]) * dis[row]
template<int K, int C>
__global__ void k_gemm_scale(const float* __restrict__ in, const float* __restrict__ W,
                             const float* __restrict__ dis, float* __restrict__ g) {
  __shared__ float Ws[K * C];
  for (int t = threadIdx.x; t < K * C; t += blockDim.x) Ws[t] = W[t];
  __syncthreads();
  constexpr int R = 256 / (C > 256 ? 256 : C);
  int t = threadIdx.x;
  int rl = t / C, c = t % C;
  int row = blockIdx.x * R + rl;
  if (row >= NN) return;
  const float* inr = in + row * K;
  float acc = 0.f;
#pragma unroll
  for (int k = 0; k < K; ++k) acc += inr[k] * Ws[k * C + c];
  g[row * C + c] = acc * dis[row];
}

// CSR gather-aggregate + self loop + *dis + bias (+tanh), fused.
// C=64: one wave per node (lane == channel).
template<bool TANH>
__global__ void k_agg64(const int* __restrict__ rowptr, const int* __restrict__ csr_src,
                        const float* __restrict__ g, const float* __restrict__ dis,
                        const float* __restrict__ b, float* __restrict__ out) {
  int node = blockIdx.x * 4 + (threadIdx.x >> 6);
  int lane = threadIdx.x & 63;
  if (node >= NN) return;
  float acc = g[node * 64 + lane];           // self loop
  int beg = rowptr[node], end = rowptr[node + 1];
  for (int k = beg; k < end; ++k) {
    int s = csr_src[k];
    acc += g[s * 64 + lane];
  }
  float v = acc * dis[node] + b[lane];
  out[node * 64 + lane] = TANH ? tanhf(v) : v;
}

// C=32: half-wave per node.
template<bool TANH>
__global__ void k_agg32(const int* __restrict__ rowptr, const int* __restrict__ csr_src,
                        const float* __restrict__ g, const float* __restrict__ dis,
                        const float* __restrict__ b, float* __restrict__ out) {
  int node = blockIdx.x * 8 + (threadIdx.x >> 5);
  int lane = threadIdx.x & 31;
  if (node >= NN) return;
  float acc = g[node * 32 + lane];
  int beg = rowptr[node], end = rowptr[node + 1];
  for (int k = beg; k < end; ++k) {
    int s = csr_src[k];
    acc += g[s * 32 + lane];
  }
  float v = acc * dis[node] + b[lane];
  out[node * 32 + lane] = TANH ? tanhf(v) : v;
}

// C=1: thread per node.
__global__ void k_agg1(const int* __restrict__ rowptr, const int* __restrict__ csr_src,
                       const float* __restrict__ g, const float* __restrict__ dis,
                       const float* __restrict__ b, float* __restrict__ out) {
  int node = blockIdx.x * blockDim.x + threadIdx.x;
  if (node >= NN) return;
  float acc = g[node];
  int beg = rowptr[node], end = rowptr[node + 1];
  for (int k = beg; k < end; ++k) acc += g[csr_src[k]];
  out[node] = acc * dis[node] + b[0];
}

extern "C" void kernel_launch(void* const* d_in, const int* in_sizes, int n_in,
                              void* d_out, int out_size, void* d_ws, size_t ws_size,
                              hipStream_t stream) {
  const float* x  = (const float*)d_in[0];
  const int*   ei = (const int*)d_in[1];
  const float* W1 = (const float*)d_in[2];
  const float* b1 = (const float*)d_in[3];
  const float* W2 = (const float*)d_in[4];
  const float* b2 = (const float*)d_in[5];
  const float* W3 = (const float*)d_in[6];
  const float* b3 = (const float*)d_in[7];
  float* out = (float*)d_out;

  char* ws = (char*)d_ws;
  int*   cnt     = (int*)ws;                        ws += ((NN + 1023)/1024)*1024 * 4;
  int*   rowptr  = (int*)ws;                        ws += ((NN + 1 + 1023)/1024)*1024 * 4;
  int*   cursor  = (int*)ws;                        ws += ((NN + 1023)/1024)*1024 * 4;
  int*   bsum    = (int*)ws;                        ws += 1024 * 4;
  int*   boff    = (int*)ws;                        ws += 1024 * 4;
  int*   csr_src = (int*)ws;                        ws += (size_t)NE * 4;
  float* dis     = (float*)ws;                      ws += ((NN + 1023)/1024)*1024 * 4;
  float* A       = (float*)ws;                      ws += (size_t)NN * 64 * 4;  // g buffer
  float* B       = (float*)ws;                      // h buffer
  // total ~ 59.3 MiB of d_ws

  // ---- CSR build + dis
  k_zero <<<(NN + 255) / 256, 256, 0, stream>>>(cnt, NN);
  k_deg  <<<(NE + 255) / 256, 256, 0, stream>>>(ei, cnt);
  k_scan1<<<NB, SCAN_B, 0, stream>>>(cnt, rowptr, bsum);
  k_scan2<<<1, 256, 0, stream>>>(bsum, boff, rowptr);
  k_scan3<<<(NN + 255) / 256, 256, 0, stream>>>(cnt, boff, rowptr, cursor, dis);
  k_fill <<<(NE + 255) / 256, 256, 0, stream>>>(ei, cursor, csr_src);

  // ---- layer 1: 64 -> 64, tanh
  k_gemm_scale<64, 64><<<(NN + 3) / 4, 256, 0, stream>>>(x, W1, dis, A);
  k_agg64<true><<<(NN + 3) / 4, 256, 0, stream>>>(rowptr, csr_src, A, dis, b1, B);

  // ---- layer 2: 64 -> 32, tanh
  k_gemm_scale<64, 32><<<(NN + 7) / 8, 256, 0, stream>>>(B, W2, dis, A);
  k_agg32<true><<<(NN + 7) / 8, 256, 0, stream>>>(rowptr, csr_src, A, dis, b2, B);

  // ---- layer 3: 32 -> 1 (no activation) -> d_out
  k_gemm_scale<32, 1><<<(NN + 255) / 256, 256, 0, stream>>>(B, W3, dis, A);
  k_agg1<<<(NN + 255) / 256, 256, 0, stream>>>(rowptr, csr_src, A, dis, b3, out);
}

// Round 4
// 517.537 us; speedup vs baseline: 1.8050x; 1.2439x over previous
//
#include <hip/hip_runtime.h>
#include <hip/hip_fp16.h>
#include <math.h>

static constexpr int NN = 100000;   // nodes
static constexpr int NE = 1600000;  // edges
static constexpr int SCAN_B = 512;  // nodes per scan block
static constexpr int NB = (NN + SCAN_B - 1) / SCAN_B;  // 196

__global__ void k_zero(int* __restrict__ p, int n) {
  int i = blockIdx.x * blockDim.x + threadIdx.x;
  if (i < n) p[i] = 0;
}

__global__ void k_deg(const int* __restrict__ ei, int* __restrict__ cnt) {
  int e = blockIdx.x * blockDim.x + threadIdx.x;
  if (e < NE) atomicAdd(&cnt[ei[NE + e]], 1);
}

// phase 1: per-block local exclusive scan -> rowptr, block sums -> bsum
__global__ __launch_bounds__(SCAN_B)
void k_scan1(const int* __restrict__ cnt, int* __restrict__ rowptr, int* __restrict__ bsum) {
  __shared__ int buf[SCAN_B];
  int tid = threadIdx.x;
  int i = blockIdx.x * SCAN_B + tid;
  int v = (i < NN) ? cnt[i] : 0;
  buf[tid] = v;
  __syncthreads();
#pragma unroll
  for (int off = 1; off < SCAN_B; off <<= 1) {
    int t = (tid >= off) ? buf[tid - off] : 0;
    __syncthreads();
    buf[tid] += t;
    __syncthreads();
  }
  if (i < NN) rowptr[i] = buf[tid] - v;   // exclusive
  if (tid == SCAN_B - 1) bsum[blockIdx.x] = buf[tid];
}

// phase 2: scan the NB block sums -> boff; total -> rowptr[NN]
__global__ __launch_bounds__(256)
void k_scan2(const int* __restrict__ bsum, int* __restrict__ boff, int* __restrict__ rowptr) {
  __shared__ int buf[256];
  int tid = threadIdx.x;
  int v = (tid < NB) ? bsum[tid] : 0;
  buf[tid] = v;
  __syncthreads();
#pragma unroll
  for (int off = 1; off < 256; off <<= 1) {
    int t = (tid >= off) ? buf[tid - off] : 0;
    __syncthreads();
    buf[tid] += t;
    __syncthreads();
  }
  if (tid < NB) boff[tid] = buf[tid] - v;
  if (tid == 255) rowptr[NN] = buf[255];
}

// phase 3: add block offsets; compute dis; init fill cursor
__global__ void k_scan3(const int* __restrict__ cnt, const int* __restrict__ boff,
                        int* __restrict__ rowptr, int* __restrict__ cursor,
                        float* __restrict__ dis) {
  int i = blockIdx.x * blockDim.x + threadIdx.x;
  if (i >= NN) return;
  int fin = rowptr[i] + boff[i / SCAN_B];
  rowptr[i] = fin;
  cursor[i] = fin;
  dis[i] = rsqrtf(1.0f + (float)cnt[i]);
}

__global__ void k_fill(const int* __restrict__ ei, int* __restrict__ cursor,
                       int* __restrict__ csr_src) {
  int e = blockIdx.x * blockDim.x + threadIdx.x;
  if (e >= NE) return;
  int src = ei[e], dst = ei[NE + e];
  int pos = atomicAdd(&cursor[dst], 1);
  csr_src[pos] = src;
}

// g[row][c] = (sum_k in[row][k] * W[k][c]) * dis[row]   (fp16 output)
template<int K, int C>
__global__ void k_gemm_scale_h(const float* __restrict__ in, const float* __restrict__ W,
                               const float* __restrict__ dis, __half* __restrict__ g) {
  __shared__ float Ws[K * C];
  for (int t = threadIdx.x; t < K * C; t += blockDim.x) Ws[t] = W[t];
  __syncthreads();
  constexpr int R = 256 / C;
  int t = threadIdx.x;
  int rl = t / C, c = t % C;
  int row = blockIdx.x * R + rl;
  if (row >= NN) return;
  const float* inr = in + row * K;
  float acc = 0.f;
#pragma unroll
  for (int k = 0; k < K; ++k) acc += inr[k] * Ws[k * C + c];
  g[row * C + c] = __float2half(acc * dis[row]);
}

// fp32 variant for the tiny last layer
template<int K, int C>
__global__ void k_gemm_scale(const float* __restrict__ in, const float* __restrict__ W,
                             const float* __restrict__ dis, float* __restrict__ g) {
  __shared__ float Ws[K * C];
  for (int t = threadIdx.x; t < K * C; t += blockDim.x) Ws[t] = W[t];
  __syncthreads();
  constexpr int R = 256 / (C > 256 ? 256 : C);
  int t = threadIdx.x;
  int rl = t / C, c = t % C;
  int row = blockIdx.x * R + rl;
  if (row >= NN) return;
  const float* inr = in + row * K;
  float acc = 0.f;
#pragma unroll
  for (int k = 0; k < K; ++k) acc += inr[k] * Ws[k * C + c];
  g[row * C + c] = acc * dis[row];
}

// CSR gather-aggregate, fp16 messages, 4-deep unrolled for MLP.
// C=64: one wave per node (lane == channel).
template<bool TANH>
__global__ void k_agg64h(const int* __restrict__ rowptr, const int* __restrict__ csr_src,
                         const __half* __restrict__ g, const float* __restrict__ dis,
                         const float* __restrict__ b, float* __restrict__ out) {
  int node = blockIdx.x * 4 + (threadIdx.x >> 6);
  int lane = threadIdx.x & 63;
  if (node >= NN) return;
  float a0 = __half2float(g[node * 64 + lane]);   // self loop
  float a1 = 0.f, a2 = 0.f, a3 = 0.f;
  int beg = rowptr[node], end = rowptr[node + 1];
  int k = beg;
  for (; k + 4 <= end; k += 4) {
    int s0 = csr_src[k], s1 = csr_src[k + 1], s2 = csr_src[k + 2], s3 = csr_src[k + 3];
    float m0 = __half2float(g[s0 * 64 + lane]);
    float m1 = __half2float(g[s1 * 64 + lane]);
    float m2 = __half2float(g[s2 * 64 + lane]);
    float m3 = __half2float(g[s3 * 64 + lane]);
    a0 += m0; a1 += m1; a2 += m2; a3 += m3;
  }
  for (; k < end; ++k) a0 += __half2float(g[csr_src[k] * 64 + lane]);
  float v = ((a0 + a1) + (a2 + a3)) * dis[node] + b[lane];
  out[node * 64 + lane] = TANH ? tanhf(v) : v;
}

// C=32: half-wave per node.
template<bool TANH>
__global__ void k_agg32h(const int* __restrict__ rowptr, const int* __restrict__ csr_src,
                         const __half* __restrict__ g, const float* __restrict__ dis,
                         const float* __restrict__ b, float* __restrict__ out) {
  int node = blockIdx.x * 8 + (threadIdx.x >> 5);
  int lane = threadIdx.x & 31;
  if (node >= NN) return;
  float a0 = __half2float(g[node * 32 + lane]);
  float a1 = 0.f, a2 = 0.f, a3 = 0.f;
  int beg = rowptr[node], end = rowptr[node + 1];
  int k = beg;
  for (; k + 4 <= end; k += 4) {
    int s0 = csr_src[k], s1 = csr_src[k + 1], s2 = csr_src[k + 2], s3 = csr_src[k + 3];
    float m0 = __half2float(g[s0 * 32 + lane]);
    float m1 = __half2float(g[s1 * 32 + lane]);
    float m2 = __half2float(g[s2 * 32 + lane]);
    float m3 = __half2float(g[s3 * 32 + lane]);
    a0 += m0; a1 += m1; a2 += m2; a3 += m3;
  }
  for (; k < end; ++k) a0 += __half2float(g[csr_src[k] * 32 + lane]);
  float v = ((a0 + a1) + (a2 + a3)) * dis[node] + b[lane];
  out[node * 32 + lane] = TANH ? tanhf(v) : v;
}

// C=1: thread per node, fp32 (tiny).
__global__ void k_agg1(const int* __restrict__ rowptr, const int* __restrict__ csr_src,
                       const float* __restrict__ g, const float* __restrict__ dis,
                       const float* __restrict__ b, float* __restrict__ out) {
  int node = blockIdx.x * blockDim.x + threadIdx.x;
  if (node >= NN) return;
  float a0 = g[node], a1 = 0.f, a2 = 0.f, a3 = 0.f;
  int beg = rowptr[node], end = rowptr[node + 1];
  int k = beg;
  for (; k + 4 <= end; k += 4) {
    float m0 = g[csr_src[k]], m1 = g[csr_src[k + 1]];
    float m2 = g[csr_src[k + 2]], m3 = g[csr_src[k + 3]];
    a0 += m0; a1 += m1; a2 += m2; a3 += m3;
  }
  for (; k < end; ++k) a0 += g[csr_src[k]];
  out[node] = ((a0 + a1) + (a2 + a3)) * dis[node] + b[0];
}

extern "C" void kernel_launch(void* const* d_in, const int* in_sizes, int n_in,
                              void* d_out, int out_size, void* d_ws, size_t ws_size,
                              hipStream_t stream) {
  const float* x  = (const float*)d_in[0];
  const int*   ei = (const int*)d_in[1];
  const float* W1 = (const float*)d_in[2];
  const float* b1 = (const float*)d_in[3];
  const float* W2 = (const float*)d_in[4];
  const float* b2 = (const float*)d_in[5];
  const float* W3 = (const float*)d_in[6];
  const float* b3 = (const float*)d_in[7];
  float* out = (float*)d_out;

  char* ws = (char*)d_ws;
  int*    cnt     = (int*)ws;     ws += ((NN + 1023)/1024)*1024 * 4;
  int*    rowptr  = (int*)ws;     ws += ((NN + 1 + 1023)/1024)*1024 * 4;
  int*    cursor  = (int*)ws;     ws += ((NN + 1023)/1024)*1024 * 4;
  int*    bsum    = (int*)ws;     ws += 1024 * 4;
  int*    boff    = (int*)ws;     ws += 1024 * 4;
  int*    csr_src = (int*)ws;     ws += (size_t)NE * 4;
  float*  dis     = (float*)ws;   ws += ((NN + 1023)/1024)*1024 * 4;
  __half* Ah      = (__half*)ws;  ws += (size_t)NN * 64 * 2;   // fp16 message table
  float*  Af      = (float*)ws;   ws += (size_t)NN * 4;        // fp32 layer-3 messages
  float*  B       = (float*)ws;   // fp32 h buffer (N*64)
  // total ~ 47 MiB of d_ws

  // ---- CSR build + dis
  k_zero <<<(NN + 255) / 256, 256, 0, stream>>>(cnt, NN);
  k_deg  <<<(NE + 255) / 256, 256, 0, stream>>>(ei, cnt);
  k_scan1<<<NB, SCAN_B, 0, stream>>>(cnt, rowptr, bsum);
  k_scan2<<<1, 256, 0, stream>>>(bsum, boff, rowptr);
  k_scan3<<<(NN + 255) / 256, 256, 0, stream>>>(cnt, boff, rowptr, cursor, dis);
  k_fill <<<(NE + 255) / 256, 256, 0, stream>>>(ei, cursor, csr_src);

  // ---- layer 1: 64 -> 64, tanh
  k_gemm_scale_h<64, 64><<<(NN + 3) / 4, 256, 0, stream>>>(x, W1, dis, Ah);
  k_agg64h<true><<<(NN + 3) / 4, 256, 0, stream>>>(rowptr, csr_src, Ah, dis, b1, B);

  // ---- layer 2: 64 -> 32, tanh
  k_gemm_scale_h<64, 32><<<(NN + 7) / 8, 256, 0, stream>>>(B, W2, dis, Ah);
  k_agg32h<true><<<(NN + 7) / 8, 256, 0, stream>>>(rowptr, csr_src, Ah, dis, b2, B);

  // ---- layer 3: 32 -> 1 (no activation) -> d_out
  k_gemm_scale<32, 1><<<(NN + 255) / 256, 256, 0, stream>>>(B, W3, dis, Af);
  k_agg1<<<(NN + 255) / 256, 256, 0, stream>>>(rowptr, csr_src, Af, dis, b3, out);
}

// Round 5
// 492.038 us; speedup vs baseline: 1.8985x; 1.0518x over previous
//
#include <hip/hip_runtime.h>
#include <hip/hip_fp16.h>
#include <math.h>

static constexpr int NN = 100000;   // nodes
static constexpr int NE = 1600000;  // edges
static constexpr int BUCK_SH = 5;   // 32 nodes per bucket
static constexpr int NBUK = NN >> BUCK_SH;  // 3125 (exact)

__global__ void k_zero(int* __restrict__ p, int n) {
  int i = blockIdx.x * blockDim.x + threadIdx.x;
  if (i < n) p[i] = 0;
}

// bucket histogram of dst, LDS-preaggregated
__global__ __launch_bounds__(256)
void k_bhist(const int* __restrict__ ei, int* __restrict__ bcnt) {
  __shared__ int h[NBUK];
  for (int i = threadIdx.x; i < NBUK; i += 256) h[i] = 0;
  __syncthreads();
  int stride = gridDim.x * 256;
  for (int e = blockIdx.x * 256 + threadIdx.x; e < NE; e += stride)
    atomicAdd(&h[ei[NE + e] >> BUCK_SH], 1);
  __syncthreads();
  for (int i = threadIdx.x; i < NBUK; i += 256) {
    int v = h[i];
    if (v) atomicAdd(&bcnt[i], v);
  }
}

// single-block scan of bucket counts -> boff (exclusive) and bcur (cursor copy)
__global__ __launch_bounds__(1024)
void k_bscan(const int* __restrict__ bcnt, int* __restrict__ boff, int* __restrict__ bcur) {
  __shared__ int buf[1024];
  __shared__ int s_carry;
  int tid = threadIdx.x;
  if (tid == 0) s_carry = 0;
  __syncthreads();
  for (int base = 0; base < NBUK; base += 1024) {
    int i = base + tid;
    int v = (i < NBUK) ? bcnt[i] : 0;
    buf[tid] = v;
    __syncthreads();
#pragma unroll
    for (int off = 1; off < 1024; off <<= 1) {
      int t = (tid >= off) ? buf[tid - off] : 0;
      __syncthreads();
      buf[tid] += t;
      __syncthreads();
    }
    int excl = buf[tid] - v;
    int carry = s_carry;
    if (i < NBUK) { boff[i] = carry + excl; bcur[i] = carry + excl; }
    __syncthreads();
    if (tid == 1023) s_carry = carry + buf[1023];
    __syncthreads();
  }
  if (tid == 0) boff[NBUK] = s_carry;   // == NE
}

// scatter packed (dst,src) into bucket-contiguous regions
__global__ void k_bscatter(const int* __restrict__ ei, int* __restrict__ bcur,
                           unsigned long long* __restrict__ se) {
  int e = blockIdx.x * blockDim.x + threadIdx.x;
  if (e >= NE) return;
  int src = ei[e], dst = ei[NE + e];
  int pos = atomicAdd(&bcur[dst >> BUCK_SH], 1);
  se[pos] = ((unsigned long long)(unsigned)dst << 32) | (unsigned)src;
}

// one block per bucket: local counting sort -> rowptr, dis, csr_src
__global__ __launch_bounds__(256)
void k_blocal(const unsigned long long* __restrict__ se, const int* __restrict__ boff,
              int* __restrict__ rowptr, float* __restrict__ dis, int* __restrict__ csr_src) {
  int b = blockIdx.x;
  int base = boff[b], end = boff[b + 1];
  __shared__ int cnt[32], off[32];
  int tid = threadIdx.x;
  if (tid < 32) cnt[tid] = 0;
  __syncthreads();
  for (int k = base + tid; k < end; k += 256)
    atomicAdd(&cnt[(int)(se[k] >> 32) & 31], 1);
  __syncthreads();
  if (tid == 0) {
    int acc = 0;
#pragma unroll
    for (int i = 0; i < 32; ++i) { off[i] = acc; acc += cnt[i]; }
  }
  __syncthreads();
  if (tid < 32) {
    int node = (b << BUCK_SH) + tid;
    rowptr[node] = base + off[tid];
    dis[node] = rsqrtf(1.0f + (float)cnt[tid]);
    cnt[tid] = 0;                       // reuse as cursor
  }
  if (b == 0 && tid == 64) rowptr[NN] = NE;
  __syncthreads();
  for (int k = base + tid; k < end; k += 256) {
    unsigned long long e = se[k];
    int dl = (int)(e >> 32) & 31;
    int pos = base + off[dl] + atomicAdd(&cnt[dl], 1);
    csr_src[pos] = (int)(e & 0xffffffffu);
  }
}

// g[row][c] = (sum_k in[row][k] * W[k][c]) * dis[row]   (fp16 output)
template<int K, int C>
__global__ void k_gemm_scale_h(const float* __restrict__ in, const float* __restrict__ W,
                               const float* __restrict__ dis, __half* __restrict__ g) {
  __shared__ float Ws[K * C];
  for (int t = threadIdx.x; t < K * C; t += blockDim.x) Ws[t] = W[t];
  __syncthreads();
  constexpr int R = 256 / C;
  int t = threadIdx.x;
  int rl = t / C, c = t % C;
  int row = blockIdx.x * R + rl;
  if (row >= NN) return;
  const float* inr = in + row * K;
  float acc = 0.f;
#pragma unroll
  for (int k = 0; k < K; ++k) acc += inr[k] * Ws[k * C + c];
  g[row * C + c] = __float2half(acc * dis[row]);
}

// fp32 variant for the tiny last layer
template<int K, int C>
__global__ void k_gemm_scale(const float* __restrict__ in, const float* __restrict__ W,
                             const float* __restrict__ dis, float* __restrict__ g) {
  __shared__ float Ws[K * C];
  for (int t = threadIdx.x; t < K * C; t += blockDim.x) Ws[t] = W[t];
  __syncthreads();
  constexpr int R = 256 / (C > 256 ? 256 : C);
  int t = threadIdx.x;
  int rl = t / C, c = t % C;
  int row = blockIdx.x * R + rl;
  if (row >= NN) return;
  const float* inr = in + row * K;
  float acc = 0.f;
#pragma unroll
  for (int k = 0; k < K; ++k) acc += inr[k] * Ws[k * C + c];
  g[row * C + c] = acc * dis[row];
}

// CSR gather-aggregate, fp16 messages, 4-deep unrolled for MLP.
template<bool TANH>
__global__ void k_agg64h(const int* __restrict__ rowptr, const int* __restrict__ csr_src,
                         const __half* __restrict__ g, const float* __restrict__ dis,
                         const float* __restrict__ b, float* __restrict__ out) {
  int node = blockIdx.x * 4 + (threadIdx.x >> 6);
  int lane = threadIdx.x & 63;
  if (node >= NN) return;
  float a0 = __half2float(g[node * 64 + lane]);   // self loop
  float a1 = 0.f, a2 = 0.f, a3 = 0.f;
  int beg = rowptr[node], end = rowptr[node + 1];
  int k = beg;
  for (; k + 4 <= end; k += 4) {
    int s0 = csr_src[k], s1 = csr_src[k + 1], s2 = csr_src[k + 2], s3 = csr_src[k + 3];
    float m0 = __half2float(g[s0 * 64 + lane]);
    float m1 = __half2float(g[s1 * 64 + lane]);
    float m2 = __half2float(g[s2 * 64 + lane]);
    float m3 = __half2float(g[s3 * 64 + lane]);
    a0 += m0; a1 += m1; a2 += m2; a3 += m3;
  }
  for (; k < end; ++k) a0 += __half2float(g[csr_src[k] * 64 + lane]);
  float v = ((a0 + a1) + (a2 + a3)) * dis[node] + b[lane];
  out[node * 64 + lane] = TANH ? tanhf(v) : v;
}

template<bool TANH>
__global__ void k_agg32h(const int* __restrict__ rowptr, const int* __restrict__ csr_src,
                         const __half* __restrict__ g, const float* __restrict__ dis,
                         const float* __restrict__ b, float* __restrict__ out) {
  int node = blockIdx.x * 8 + (threadIdx.x >> 5);
  int lane = threadIdx.x & 31;
  if (node >= NN) return;
  float a0 = __half2float(g[node * 32 + lane]);
  float a1 = 0.f, a2 = 0.f, a3 = 0.f;
  int beg = rowptr[node], end = rowptr[node + 1];
  int k = beg;
  for (; k + 4 <= end; k += 4) {
    int s0 = csr_src[k], s1 = csr_src[k + 1], s2 = csr_src[k + 2], s3 = csr_src[k + 3];
    float m0 = __half2float(g[s0 * 32 + lane]);
    float m1 = __half2float(g[s1 * 32 + lane]);
    float m2 = __half2float(g[s2 * 32 + lane]);
    float m3 = __half2float(g[s3 * 32 + lane]);
    a0 += m0; a1 += m1; a2 += m2; a3 += m3;
  }
  for (; k < end; ++k) a0 += __half2float(g[csr_src[k] * 32 + lane]);
  float v = ((a0 + a1) + (a2 + a3)) * dis[node] + b[lane];
  out[node * 32 + lane] = TANH ? tanhf(v) : v;
}

__global__ void k_agg1(const int* __restrict__ rowptr, const int* __restrict__ csr_src,
                       const float* __restrict__ g, const float* __restrict__ dis,
                       const float* __restrict__ b, float* __restrict__ out) {
  int node = blockIdx.x * blockDim.x + threadIdx.x;
  if (node >= NN) return;
  float a0 = g[node], a1 = 0.f, a2 = 0.f, a3 = 0.f;
  int beg = rowptr[node], end = rowptr[node + 1];
  int k = beg;
  for (; k + 4 <= end; k += 4) {
    float m0 = g[csr_src[k]], m1 = g[csr_src[k + 1]];
    float m2 = g[csr_src[k + 2]], m3 = g[csr_src[k + 3]];
    a0 += m0; a1 += m1; a2 += m2; a3 += m3;
  }
  for (; k < end; ++k) a0 += g[csr_src[k]];
  out[node] = ((a0 + a1) + (a2 + a3)) * dis[node] + b[0];
}

extern "C" void kernel_launch(void* const* d_in, const int* in_sizes, int n_in,
                              void* d_out, int out_size, void* d_ws, size_t ws_size,
                              hipStream_t stream) {
  const float* x  = (const float*)d_in[0];
  const int*   ei = (const int*)d_in[1];
  const float* W1 = (const float*)d_in[2];
  const float* b1 = (const float*)d_in[3];
  const float* W2 = (const float*)d_in[4];
  const float* b2 = (const float*)d_in[5];
  const float* W3 = (const float*)d_in[6];
  const float* b3 = (const float*)d_in[7];
  float* out = (float*)d_out;

  char* ws = (char*)d_ws;
  unsigned long long* se = (unsigned long long*)ws;  ws += (size_t)NE * 8;  // 8B-aligned first
  int*    bcnt    = (int*)ws;     ws += ((NBUK + 255)/256)*256 * 4;
  int*    boff    = (int*)ws;     ws += ((NBUK + 1 + 255)/256)*256 * 4;
  int*    bcur    = (int*)ws;     ws += ((NBUK + 255)/256)*256 * 4;
  int*    rowptr  = (int*)ws;     ws += ((NN + 1 + 255)/256)*256 * 4;
  int*    csr_src = (int*)ws;     ws += (size_t)NE * 4;
  float*  dis     = (float*)ws;   ws += ((NN + 255)/256)*256 * 4;
  __half* Ah      = (__half*)ws;  ws += (size_t)NN * 64 * 2;   // fp16 message table
  float*  Af      = (float*)ws;   ws += (size_t)NN * 4;        // fp32 layer-3 messages
  float*  B       = (float*)ws;   // fp32 h buffer (N*64)
  // total ~ 59 MiB of d_ws

  // ---- CSR build (bucketed counting sort) + dis
  k_zero    <<<(NBUK + 255) / 256, 256, 0, stream>>>(bcnt, NBUK);
  k_bhist   <<<128, 256, 0, stream>>>(ei, bcnt);
  k_bscan   <<<1, 1024, 0, stream>>>(bcnt, boff, bcur);
  k_bscatter<<<(NE + 255) / 256, 256, 0, stream>>>(ei, bcur, se);
  k_blocal  <<<NBUK, 256, 0, stream>>>(se, boff, rowptr, dis, csr_src);

  // ---- layer 1: 64 -> 64, tanh
  k_gemm_scale_h<64, 64><<<(NN + 3) / 4, 256, 0, stream>>>(x, W1, dis, Ah);
  k_agg64h<true><<<(NN + 3) / 4, 256, 0, stream>>>(rowptr, csr_src, Ah, dis, b1, B);

  // ---- layer 2: 64 -> 32, tanh
  k_gemm_scale_h<64, 32><<<(NN + 7) / 8, 256, 0, stream>>>(B, W2, dis, Ah);
  k_agg32h<true><<<(NN + 7) / 8, 256, 0, stream>>>(rowptr, csr_src, Ah, dis, b2, B);

  // ---- layer 3: 32 -> 1 (no activation) -> d_out
  k_gemm_scale<32, 1><<<(NN + 255) / 256, 256, 0, stream>>>(B, W3, dis, Af);
  k_agg1<<<(NN + 255) / 256, 256, 0, stream>>>(rowptr, csr_src, Af, dis, b3, out);
}

// Round 6
// 392.096 us; speedup vs baseline: 2.3824x; 1.2549x over previous
//
#include <hip/hip_runtime.h>
#include <hip/hip_fp16.h>
#include <math.h>

static constexpr int NN = 100000;   // nodes
static constexpr int NE = 1600000;  // edges
static constexpr int BUCK_SH = 5;   // 32 nodes per bucket
static constexpr int NBUK = NN >> BUCK_SH;   // 3125 (exact)
static constexpr int NCH = 64;               // chunks (one scat block each)
static constexpr int CH = NE / NCH;          // 25000 edges per chunk (exact)
static constexpr int SUB = 4;                // hist sub-blocks per chunk
static constexpr int SUBE = CH / SUB;        // 6250 edges per hist block

__global__ void k_zero(int* __restrict__ p, int n) {
  int i = blockIdx.x * blockDim.x + threadIdx.x;
  if (i < n) p[i] = 0;
}

// pass 1: per-chunk bucket histogram H[chunk][bucket], LDS-staged
__global__ __launch_bounds__(256)
void k_chist(const int* __restrict__ ei, int* __restrict__ H) {
  __shared__ int h[NBUK];
  for (int i = threadIdx.x; i < NBUK; i += 256) h[i] = 0;
  __syncthreads();
  int chunk = blockIdx.x / SUB, sub = blockIdx.x % SUB;
  int start = chunk * CH + sub * SUBE;
  for (int e = start + threadIdx.x; e < start + SUBE; e += 256)
    atomicAdd(&h[ei[NE + e] >> BUCK_SH], 1);
  __syncthreads();
  int* Hc = H + chunk * NBUK;
  for (int i = threadIdx.x; i < NBUK; i += 256) {
    int v = h[i];
    if (v) atomicAdd(&Hc[i], v);
  }
}

// pass 2: in-place exclusive prefix over chunks per bucket; totals -> tot
__global__ void k_csum(int* __restrict__ H, int* __restrict__ tot) {
  int b = blockIdx.x * blockDim.x + threadIdx.x;
  if (b >= NBUK) return;
  int acc = 0;
#pragma unroll 4
  for (int c = 0; c < NCH; ++c) {
    int v = H[c * NBUK + b];
    H[c * NBUK + b] = acc;
    acc += v;
  }
  tot[b] = acc;
}

// single-block scan of bucket totals -> boff (exclusive), boff[NBUK]=NE
__global__ __launch_bounds__(1024)
void k_bscan(const int* __restrict__ tot, int* __restrict__ boff) {
  __shared__ int buf[1024];
  __shared__ int s_carry;
  int tid = threadIdx.x;
  if (tid == 0) s_carry = 0;
  __syncthreads();
  for (int base = 0; base < NBUK; base += 1024) {
    int i = base + tid;
    int v = (i < NBUK) ? tot[i] : 0;
    buf[tid] = v;
    __syncthreads();
#pragma unroll
    for (int off = 1; off < 1024; off <<= 1) {
      int t = (tid >= off) ? buf[tid - off] : 0;
      __syncthreads();
      buf[tid] += t;
      __syncthreads();
    }
    int excl = buf[tid] - v;
    int carry = s_carry;
    if (i < NBUK) boff[i] = carry + excl;
    __syncthreads();
    if (tid == 1023) s_carry = carry + buf[1023];
    __syncthreads();
  }
  if (tid == 0) boff[NBUK] = s_carry;   // == NE
}

// pass 3: one block per chunk; LDS cursors; write packed (dstLow5,src) u32
// grouped by bucket. All stores of a run come from this block -> full lines.
__global__ __launch_bounds__(1024)
void k_scat(const int* __restrict__ ei, const int* __restrict__ H,
            const int* __restrict__ boff, unsigned* __restrict__ se) {
  __shared__ int cur[NBUK];
  int chunk = blockIdx.x;
  const int* Hc = H + chunk * NBUK;
  for (int i = threadIdx.x; i < NBUK; i += 1024) cur[i] = boff[i] + Hc[i];
  __syncthreads();
  int start = chunk * CH;
  for (int e = start + threadIdx.x; e < start + CH; e += 1024) {
    int src = ei[e], dst = ei[NE + e];
    int pos = atomicAdd(&cur[dst >> BUCK_SH], 1);
    se[pos] = ((unsigned)(dst & 31) << 20) | (unsigned)src;   // src < 2^17
  }
}

// one block per bucket: local counting sort -> rowptr, dis, csr_src
__global__ __launch_bounds__(256)
void k_blocal(const unsigned* __restrict__ se, const int* __restrict__ boff,
              int* __restrict__ rowptr, float* __restrict__ dis, int* __restrict__ csr_src) {
  int b = blockIdx.x;
  int base = boff[b], end = boff[b + 1];
  __shared__ int cnt[32], off[32];
  int tid = threadIdx.x;
  if (tid < 32) cnt[tid] = 0;
  __syncthreads();
  for (int k = base + tid; k < end; k += 256)
    atomicAdd(&cnt[se[k] >> 20], 1);
  __syncthreads();
  if (tid == 0) {
    int acc = 0;
#pragma unroll
    for (int i = 0; i < 32; ++i) { off[i] = acc; acc += cnt[i]; }
  }
  __syncthreads();
  if (tid < 32) {
    int node = (b << BUCK_SH) + tid;
    rowptr[node] = base + off[tid];
    dis[node] = rsqrtf(1.0f + (float)cnt[tid]);
    cnt[tid] = 0;                       // reuse as cursor
  }
  if (b == 0 && tid == 64) rowptr[NN] = NE;
  __syncthreads();
  for (int k = base + tid; k < end; k += 256) {
    unsigned e = se[k];
    int dl = e >> 20;
    int pos = base + off[dl] + atomicAdd(&cnt[dl], 1);
    csr_src[pos] = (int)(e & 0xFFFFFu);
  }
}

// g[row][c] = (sum_k in[row][k] * W[k][c]) * dis[row]   (fp16 output)
template<int K, int C>
__global__ void k_gemm_scale_h(const float* __restrict__ in, const float* __restrict__ W,
                               const float* __restrict__ dis, __half* __restrict__ g) {
  __shared__ float Ws[K * C];
  for (int t = threadIdx.x; t < K * C; t += blockDim.x) Ws[t] = W[t];
  __syncthreads();
  constexpr int R = 256 / C;
  int t = threadIdx.x;
  int rl = t / C, c = t % C;
  int row = blockIdx.x * R + rl;
  if (row >= NN) return;
  const float* inr = in + row * K;
  float acc = 0.f;
#pragma unroll
  for (int k = 0; k < K; ++k) acc += inr[k] * Ws[k * C + c];
  g[row * C + c] = __float2half(acc * dis[row]);
}

// fp32 variant for the tiny last layer
template<int K, int C>
__global__ void k_gemm_scale(const float* __restrict__ in, const float* __restrict__ W,
                             const float* __restrict__ dis, float* __restrict__ g) {
  __shared__ float Ws[K * C];
  for (int t = threadIdx.x; t < K * C; t += blockDim.x) Ws[t] = W[t];
  __syncthreads();
  constexpr int R = 256 / (C > 256 ? 256 : C);
  int t = threadIdx.x;
  int rl = t / C, c = t % C;
  int row = blockIdx.x * R + rl;
  if (row >= NN) return;
  const float* inr = in + row * K;
  float acc = 0.f;
#pragma unroll
  for (int k = 0; k < K; ++k) acc += inr[k] * Ws[k * C + c];
  g[row * C + c] = acc * dis[row];
}

// CSR gather-aggregate, fp16 messages, 4-deep unrolled for MLP.
template<bool TANH>
__global__ void k_agg64h(const int* __restrict__ rowptr, const int* __restrict__ csr_src,
                         const __half* __restrict__ g, const float* __restrict__ dis,
                         const float* __restrict__ b, float* __restrict__ out) {
  int node = blockIdx.x * 4 + (threadIdx.x >> 6);
  int lane = threadIdx.x & 63;
  if (node >= NN) return;
  float a0 = __half2float(g[node * 64 + lane]);   // self loop
  float a1 = 0.f, a2 = 0.f, a3 = 0.f;
  int beg = rowptr[node], end = rowptr[node + 1];
  int k = beg;
  for (; k + 4 <= end; k += 4) {
    int s0 = csr_src[k], s1 = csr_src[k + 1], s2 = csr_src[k + 2], s3 = csr_src[k + 3];
    float m0 = __half2float(g[s0 * 64 + lane]);
    float m1 = __half2float(g[s1 * 64 + lane]);
    float m2 = __half2float(g[s2 * 64 + lane]);
    float m3 = __half2float(g[s3 * 64 + lane]);
    a0 += m0; a1 += m1; a2 += m2; a3 += m3;
  }
  for (; k < end; ++k) a0 += __half2float(g[csr_src[k] * 64 + lane]);
  float v = ((a0 + a1) + (a2 + a3)) * dis[node] + b[lane];
  out[node * 64 + lane] = TANH ? tanhf(v) : v;
}

template<bool TANH>
__global__ void k_agg32h(const int* __restrict__ rowptr, const int* __restrict__ csr_src,
                         const __half* __restrict__ g, const float* __restrict__ dis,
                         const float* __restrict__ b, float* __restrict__ out) {
  int node = blockIdx.x * 8 + (threadIdx.x >> 5);
  int lane = threadIdx.x & 31;
  if (node >= NN) return;
  float a0 = __half2float(g[node * 32 + lane]);
  float a1 = 0.f, a2 = 0.f, a3 = 0.f;
  int beg = rowptr[node], end = rowptr[node + 1];
  int k = beg;
  for (; k + 4 <= end; k += 4) {
    int s0 = csr_src[k], s1 = csr_src[k + 1], s2 = csr_src[k + 2], s3 = csr_src[k + 3];
    float m0 = __half2float(g[s0 * 32 + lane]);
    float m1 = __half2float(g[s1 * 32 + lane]);
    float m2 = __half2float(g[s2 * 32 + lane]);
    float m3 = __half2float(g[s3 * 32 + lane]);
    a0 += m0; a1 += m1; a2 += m2; a3 += m3;
  }
  for (; k < end; ++k) a0 += __half2float(g[csr_src[k] * 32 + lane]);
  float v = ((a0 + a1) + (a2 + a3)) * dis[node] + b[lane];
  out[node * 32 + lane] = TANH ? tanhf(v) : v;
}

__global__ void k_agg1(const int* __restrict__ rowptr, const int* __restrict__ csr_src,
                       const float* __restrict__ g, const float* __restrict__ dis,
                       const float* __restrict__ b, float* __restrict__ out) {
  int node = blockIdx.x * blockDim.x + threadIdx.x;
  if (node >= NN) return;
  float a0 = g[node], a1 = 0.f, a2 = 0.f, a3 = 0.f;
  int beg = rowptr[node], end = rowptr[node + 1];
  int k = beg;
  for (; k + 4 <= end; k += 4) {
    float m0 = g[csr_src[k]], m1 = g[csr_src[k + 1]];
    float m2 = g[csr_src[k + 2]], m3 = g[csr_src[k + 3]];
    a0 += m0; a1 += m1; a2 += m2; a3 += m3;
  }
  for (; k < end; ++k) a0 += g[csr_src[k]];
  out[node] = ((a0 + a1) + (a2 + a3)) * dis[node] + b[0];
}

extern "C" void kernel_launch(void* const* d_in, const int* in_sizes, int n_in,
                              void* d_out, int out_size, void* d_ws, size_t ws_size,
                              hipStream_t stream) {
  const float* x  = (const float*)d_in[0];
  const int*   ei = (const int*)d_in[1];
  const float* W1 = (const float*)d_in[2];
  const float* b1 = (const float*)d_in[3];
  const float* W2 = (const float*)d_in[4];
  const float* b2 = (const float*)d_in[5];
  const float* W3 = (const float*)d_in[6];
  const float* b3 = (const float*)d_in[7];
  float* out = (float*)d_out;

  char* ws = (char*)d_ws;
  int*      H       = (int*)ws;      ws += (size_t)NCH * NBUK * 4;          // 800 KB
  int*      tot     = (int*)ws;      ws += ((NBUK + 255)/256)*256 * 4;
  int*      boff    = (int*)ws;      ws += ((NBUK + 1 + 255)/256)*256 * 4;
  unsigned* se      = (unsigned*)ws; ws += (size_t)NE * 4;                  // 6.4 MB
  int*      rowptr  = (int*)ws;      ws += ((NN + 1 + 255)/256)*256 * 4;
  int*      csr_src = (int*)ws;      ws += (size_t)NE * 4;                  // 6.4 MB
  float*    dis     = (float*)ws;    ws += ((NN + 255)/256)*256 * 4;
  __half*   Ah      = (__half*)ws;   ws += (size_t)NN * 64 * 2;             // 12.8 MB
  float*    Af      = (float*)ws;    ws += (size_t)NN * 4;
  float*    B       = (float*)ws;    // fp32 h buffer (N*64), 25.6 MB
  // total ~ 53 MiB of d_ws

  // ---- CSR build (deterministic two-pass counting sort) + dis
  k_zero  <<<(NCH * NBUK + 255) / 256, 256, 0, stream>>>(H, NCH * NBUK);
  k_chist <<<NCH * SUB, 256, 0, stream>>>(ei, H);
  k_csum  <<<(NBUK + 255) / 256, 256, 0, stream>>>(H, tot);
  k_bscan <<<1, 1024, 0, stream>>>(tot, boff);
  k_scat  <<<NCH, 1024, 0, stream>>>(ei, H, boff, se);
  k_blocal<<<NBUK, 256, 0, stream>>>(se, boff, rowptr, dis, csr_src);

  // ---- layer 1: 64 -> 64, tanh
  k_gemm_scale_h<64, 64><<<(NN + 3) / 4, 256, 0, stream>>>(x, W1, dis, Ah);
  k_agg64h<true><<<(NN + 3) / 4, 256, 0, stream>>>(rowptr, csr_src, Ah, dis, b1, B);

  // ---- layer 2: 64 -> 32, tanh
  k_gemm_scale_h<64, 32><<<(NN + 7) / 8, 256, 0, stream>>>(B, W2, dis, Ah);
  k_agg32h<true><<<(NN + 7) / 8, 256, 0, stream>>>(rowptr, csr_src, Ah, dis, b2, B);

  // ---- layer 3: 32 -> 1 (no activation) -> d_out
  k_gemm_scale<32, 1><<<(NN + 255) / 256, 256, 0, stream>>>(B, W3, dis, Af);
  k_agg1<<<(NN + 255) / 256, 256, 0, stream>>>(rowptr, csr_src, Af, dis, b3, out);
}